// Round 12
// baseline (1589.238 us; speedup 1.0000x reference)
//
#include <hip/hip_runtime.h>
#include <hip/hip_bf16.h>
#include <cmath>

#define IMG_DIM 512
#define D_MODEL 768
#define N_LAYER 12
#define D_INNER 1536
#define D_STATE 16
#define D_CONV 4
#define DT_RANK 48
#define BATCH 4
#define SEQ 256
#define M_TOK (BATCH * SEQ)               // 1024 token rows
#define XPROJ_N (DT_RANK + 2 * D_STATE)   // 80
#define KSPLIT 8
#define NCHUNK 16
#define CLEN 16                           // SEQ / NCHUNK
#define LOG2E 1.4426950408889634f

typedef __attribute__((ext_vector_type(8))) short bf16x8;
typedef __attribute__((ext_vector_type(8))) unsigned short u16x8;
typedef __attribute__((ext_vector_type(4))) float f32x4;
typedef __hip_bfloat16 bf16;

__device__ __forceinline__ float softplus_f(float v) {
    return v > 20.f ? v : log1pf(expf(v));
}
__device__ __forceinline__ float b2f(bf16 v) { return __bfloat162float(v); }
__device__ __forceinline__ float us2f(unsigned short v) {
    return __uint_as_float(((unsigned)v) << 16);
}

// async global->LDS, 16B per lane; LDS dest is wave-uniform base + lane*16
__device__ __forceinline__ void gl_lds16(const char* g, char* l) {
    __builtin_amdgcn_global_load_lds(
        (const __attribute__((address_space(1))) unsigned int*)g,
        (__attribute__((address_space(3))) unsigned int*)l,
        16, 0, 0);
}

// ---------------------------------------------------------------------------
// Weight transpose + fp32->bf16: W[z][K][N] -> WT[z][N][K]; N-guarded.
// ---------------------------------------------------------------------------
__global__ __launch_bounds__(256) void wcvt_t_k(
    const float* __restrict__ W, bf16* __restrict__ WT, int K, int N)
{
    __shared__ float tile[32][33];
    W  += (size_t)blockIdx.z * K * N;
    WT += (size_t)blockIdx.z * K * N;
    const int tx = threadIdx.x & 31;
    const int ty4 = (threadIdx.x >> 5) * 4;
    const int n0 = blockIdx.x * 32, k0 = blockIdx.y * 32;
    #pragma unroll
    for (int r = 0; r < 4; ++r)
        tile[ty4 + r][tx] = (n0 + tx < N)
            ? W[(size_t)(k0 + ty4 + r) * N + n0 + tx] : 0.f;
    __syncthreads();
    #pragma unroll
    for (int r = 0; r < 4; ++r)
        if (n0 + ty4 + r < N)
            WT[(size_t)(n0 + ty4 + r) * K + k0 + tx] =
                __float2bfloat16(tile[tx][ty4 + r]);
}

// ---------------------------------------------------------------------------
// Flat fp32 -> bf16 convert
// ---------------------------------------------------------------------------
__global__ __launch_bounds__(256) void cvt_bf16_k(
    const float* __restrict__ in, bf16* __restrict__ out, int n)
{
    int i = blockIdx.x * 256 + threadIdx.x;
    if (i < n) out[i] = __float2bfloat16(in[i]);
}

// ---------------------------------------------------------------------------
// dt_w (all layers) [12][48][1536] -> dt_wT [12][1536][64], zero-pad k 48..63
// ---------------------------------------------------------------------------
__global__ __launch_bounds__(256) void dtw_cvt_k(
    const float* __restrict__ dt_w, bf16* __restrict__ dtwT)
{
    int idx = blockIdx.x * 256 + threadIdx.x;   // over 12*1536*64
    int k = idx & 63;
    int n = (idx >> 6) % D_INNER;
    int l = idx / (64 * D_INNER);
    dtwT[idx] = (k < DT_RANK)
        ? __float2bfloat16(dt_w[((size_t)l * DT_RANK + k) * D_INNER + n])
        : bf16(0.f);
}

// ---------------------------------------------------------------------------
// A2 (all layers): A2[l][d][n] = -exp(A_log[l][d][n]) * log2(e)
// ---------------------------------------------------------------------------
__global__ __launch_bounds__(256) void a2_k(
    const float* __restrict__ A_log, float* __restrict__ A2)
{
    int idx = blockIdx.x * 256 + threadIdx.x;   // < 12*1536*16
    A2[idx] = -expf(A_log[idx]) * LOG2E;
}

// ---------------------------------------------------------------------------
// bf16 MFMA GEMM, 64x64 tile (4 waves 2x2) — R10-proven.
// EPI: 0 = store, 1 = bias+relu, 3 = accumulate
// ---------------------------------------------------------------------------
template <int EPI, typename OT>
__global__ __launch_bounds__(256) void gemm_bf16(
    const bf16* __restrict__ A,
    const bf16* __restrict__ BT,
    OT* __restrict__ C, int ldc, int K,
    const float* __restrict__ bias)
{
    __shared__ __align__(16) char lds[2][16384];   // [buf][A 8K | B 8K]
    const int tid = threadIdx.x;
    const int lane = tid & 63;
    const int wid = tid >> 6;
    const int wr = wid >> 1, wc = wid & 1;
    const size_t rowBase = blockIdx.x * 64;
    const size_t colBase = blockIdx.y * 64;

    const int r0 = tid >> 3;
    const int cb0 = (tid & 7) * 16;
    const int slot = tid * 16;
    const size_t gOffSw = (size_t)r0 * K * 2 + (cb0 ^ ((r0 & 7) << 4));
    const size_t aStep = (size_t)32 * K * 2;   // +32 rows
    const char* gA = (const char*)(A + rowBase * K);
    const char* gB = (const char*)(BT + colBase * K);

    const int lrow = lane & 15;
    const int kg = (lane >> 4) * 16;
    const int swz = (lane & 7) << 4;

    f32x4 acc[2][2] = {};
    const int nt = K >> 6;

    {
        char* L = &lds[0][0];
        gl_lds16(gA + gOffSw,          L + slot);
        gl_lds16(gA + gOffSw + aStep,  L + 4096 + slot);
        gl_lds16(gB + gOffSw,          L + 8192 + slot);
        gl_lds16(gB + gOffSw + aStep,  L + 12288 + slot);
    }
    __syncthreads();

    for (int t = 0; t < nt; ++t) {
        const int cur = t & 1;
        if (t + 1 < nt) {
            char* L = &lds[cur ^ 1][0];
            size_t go = gOffSw + (size_t)(t + 1) * 128;
            gl_lds16(gA + go,          L + slot);
            gl_lds16(gA + go + aStep,  L + 4096 + slot);
            gl_lds16(gB + go,          L + 8192 + slot);
            gl_lds16(gB + go + aStep,  L + 12288 + slot);
        }
        #pragma unroll
        for (int kk = 0; kk < 2; ++kk) {
            const int col = (kk * 64 + kg) ^ swz;
            bf16x8 a0 = *(const bf16x8*)(&lds[cur][(wr * 32 +      lrow) * 128 + col]);
            bf16x8 a1 = *(const bf16x8*)(&lds[cur][(wr * 32 + 16 + lrow) * 128 + col]);
            bf16x8 b0 = *(const bf16x8*)(&lds[cur][8192 + (wc * 32 +      lrow) * 128 + col]);
            bf16x8 b1 = *(const bf16x8*)(&lds[cur][8192 + (wc * 32 + 16 + lrow) * 128 + col]);
            acc[0][0] = __builtin_amdgcn_mfma_f32_16x16x32_bf16(a0, b0, acc[0][0], 0, 0, 0);
            acc[0][1] = __builtin_amdgcn_mfma_f32_16x16x32_bf16(a0, b1, acc[0][1], 0, 0, 0);
            acc[1][0] = __builtin_amdgcn_mfma_f32_16x16x32_bf16(a1, b0, acc[1][0], 0, 0, 0);
            acc[1][1] = __builtin_amdgcn_mfma_f32_16x16x32_bf16(a1, b1, acc[1][1], 0, 0, 0);
        }
        __syncthreads();
    }

    const int mBase = (int)rowBase + wr * 32 + (lane >> 4) * 4;
    const int nBase = (int)colBase + wc * 32 + (lane & 15);
    #pragma unroll
    for (int i = 0; i < 2; ++i)
        #pragma unroll
        for (int j = 0; j < 2; ++j)
            #pragma unroll
            for (int rg = 0; rg < 4; ++rg) {
                int cc = nBase + j * 16;
                size_t idx = (size_t)(mBase + i * 16 + rg) * ldc + cc;
                float v = acc[i][j][rg];
                if (EPI == 0) {
                    C[idx] = (OT)v;
                } else if (EPI == 1) {
                    v += bias[cc];
                    C[idx] = (OT)(v > 0.f ? v : 0.f);
                } else {
                    C[idx] += v;
                }
            }
}

// ---------------------------------------------------------------------------
// Skinny split-K MFMA GEMM for xproj (no LDS)
// ---------------------------------------------------------------------------
__global__ __launch_bounds__(256) void xproj_gemm_k(
    const bf16* __restrict__ xc_bf,
    const bf16* __restrict__ xprojT,
    float* __restrict__ part)
{
    const int lane = threadIdx.x & 63;
    const int w = threadIdx.x >> 6;
    const int m0 = blockIdx.x * 64 + w * 16;
    const int ks = blockIdx.y;
    const int KS = D_INNER / KSPLIT;          // 192
    const int k0 = ks * KS;

    const int arow = m0 + (lane & 15);
    const int kgrp = (lane >> 4) * 8;

    f32x4 acc[5] = {};
    const bf16* ap = xc_bf + (size_t)arow * D_INNER + kgrp;
    const bf16* bp = xprojT + (size_t)(lane & 15) * D_INNER + kgrp;

    for (int k = k0; k < k0 + KS; k += 32) {
        bf16x8 a = *(const bf16x8*)(ap + k);
        #pragma unroll
        for (int f = 0; f < 5; ++f) {
            bf16x8 b = *(const bf16x8*)(bp + (size_t)f * 16 * D_INNER + k);
            acc[f] = __builtin_amdgcn_mfma_f32_16x16x32_bf16(a, b, acc[f], 0, 0, 0);
        }
    }

    float* out = part + (size_t)ks * M_TOK * XPROJ_N;
    const int rowb = blockIdx.x * 64 + w * 16 + (lane >> 4) * 4;
    #pragma unroll
    for (int f = 0; f < 5; ++f)
        #pragma unroll
        for (int rg = 0; rg < 4; ++rg)
            out[(size_t)(rowb + rg) * XPROJ_N + f * 16 + (lane & 15)] = acc[f][rg];
}

// ---------------------------------------------------------------------------
// Fused: reduce split-K partials (64 rows x 80 cols) -> xdbl (y==0 blocks)
// + stage dtin rows in LDS (zero-padded K 48..63, row pad 72 for banks)
// + dt MFMA (K=64) + bias + softplus -> delta_bf. Grid (16, 24), 256 thr.
// ---------------------------------------------------------------------------
__global__ __launch_bounds__(256) void xred_dt_k(
    const float* __restrict__ part,
    const bf16* __restrict__ dt_wT,    // layer slice [1536][64]
    const float* __restrict__ dt_b,
    float* __restrict__ xdbl,
    bf16* __restrict__ delta)
{
    __shared__ bf16 sdt[64][72];
    const int tid = threadIdx.x;
    const int m0 = blockIdx.x * 64;
    const int n0 = blockIdx.y * 64;

    // zero pad cols 48..63 (rows 0..63, 4 cols per thread)
    {
        int r = tid >> 2, c = 48 + (tid & 3) * 4;
        ushort4 z = {0, 0, 0, 0};
        *(ushort4*)&sdt[r][c] = z;
    }

    // reduce partials for this block's 64 rows x 80 cols
    #pragma unroll
    for (int j = 0; j < 20; ++j) {
        int idx = tid + j * 256;                 // < 5120
        float s = 0.f;
        #pragma unroll
        for (int p = 0; p < KSPLIT; ++p)
            s += part[(size_t)p * M_TOK * XPROJ_N + (size_t)m0 * XPROJ_N + idx];
        if (blockIdx.y == 0)
            xdbl[(size_t)m0 * XPROJ_N + idx] = s;
        int r = idx / XPROJ_N, c = idx - r * XPROJ_N;
        if (c < DT_RANK) sdt[r][c] = __float2bfloat16(s);
    }
    __syncthreads();

    // dt MFMA: 4 waves x 16 rows; A from LDS, B from global dt_wT
    const int lane = tid & 63, w = tid >> 6;
    const int lrow = w * 16 + (lane & 15);
    const int kgrp = (lane >> 4) * 8;
    const bf16* bp = dt_wT + (size_t)(n0 + (lane & 15)) * 64 + kgrp;

    f32x4 acc[4] = {};
    #pragma unroll
    for (int k = 0; k < 64; k += 32) {
        bf16x8 a = *(const bf16x8*)&sdt[lrow][kgrp + k];
        #pragma unroll
        for (int f = 0; f < 4; ++f) {
            bf16x8 b = *(const bf16x8*)(bp + (size_t)f * 16 * 64 + k);
            acc[f] = __builtin_amdgcn_mfma_f32_16x16x32_bf16(a, b, acc[f], 0, 0, 0);
        }
    }

    const int rowb = m0 + w * 16 + (lane >> 4) * 4;
    #pragma unroll
    for (int f = 0; f < 4; ++f) {
        int cc = n0 + f * 16 + (lane & 15);
        float bias = dt_b[cc];
        #pragma unroll
        for (int rg = 0; rg < 4; ++rg)
            delta[(size_t)(rowb + rg) * D_INNER + cc] =
                __float2bfloat16(softplus_f(acc[f][rg] + bias));
    }
}

// ---------------------------------------------------------------------------
// RMSNorm: one block per token row; templated output type
// ---------------------------------------------------------------------------
template <typename OT>
__global__ __launch_bounds__(256) void rmsnorm_k(
    const float* __restrict__ x, const float* __restrict__ w,
    OT* __restrict__ o)
{
    const int row = blockIdx.x;
    const float* xr = x + (size_t)row * D_MODEL;
    float v[3];
    float s = 0.f;
    #pragma unroll
    for (int i = 0; i < 3; ++i) {
        v[i] = xr[threadIdx.x + i * 256];
        s = fmaf(v[i], v[i], s);
    }
    #pragma unroll
    for (int off = 32; off > 0; off >>= 1) s += __shfl_down(s, off);
    __shared__ float red[4];
    if ((threadIdx.x & 63) == 0) red[threadIdx.x >> 6] = s;
    __syncthreads();
    float tot = red[0] + red[1] + red[2] + red[3];
    float r = rsqrtf(tot * (1.f / D_MODEL) + 1e-5f);
    OT* orow = o + (size_t)row * D_MODEL;
    #pragma unroll
    for (int i = 0; i < 3; ++i) {
        int c = threadIdx.x + i * 256;
        orow[c] = (OT)(v[i] * r * w[c]);
    }
}

// ---------------------------------------------------------------------------
// Causal depthwise conv (width 4) + bias + silu; vectorized 8 d / thread
// ---------------------------------------------------------------------------
__global__ __launch_bounds__(256) void conv_silu_k(
    const bf16* __restrict__ xz, const float* __restrict__ cw,
    const float* __restrict__ cb, bf16* __restrict__ xc_bf)
{
    int v = blockIdx.x * 256 + threadIdx.x;   // over M_TOK*D_INNER/8
    int d8 = (v * 8) % D_INNER;
    int bt = (v * 8) / D_INNER;
    int t = bt & (SEQ - 1);
    int b = bt >> 8;

    float acc[8];
    {
        const float4* cbp = (const float4*)(cb + d8);
        float4 c0 = cbp[0], c1 = cbp[1];
        acc[0] = c0.x; acc[1] = c0.y; acc[2] = c0.z; acc[3] = c0.w;
        acc[4] = c1.x; acc[5] = c1.y; acc[6] = c1.z; acc[7] = c1.w;
    }
    float4 wv[8];
    #pragma unroll
    for (int j = 0; j < 8; ++j)
        wv[j] = *(const float4*)(cw + (size_t)(d8 + j) * 4);

    #pragma unroll
    for (int k = 0; k < 4; ++k) {
        int tt = t - 3 + k;
        if (tt >= 0) {
            u16x8 xv = *(const u16x8*)(xz + (size_t)(b * SEQ + tt) * (2 * D_INNER) + d8);
            #pragma unroll
            for (int j = 0; j < 8; ++j) {
                float wk = (k == 0) ? wv[j].x : (k == 1) ? wv[j].y
                         : (k == 2) ? wv[j].z : wv[j].w;
                acc[j] = fmaf(us2f(xv[j]), wk, acc[j]);
            }
        }
    }

    __align__(16) bf16 ob[8];
    #pragma unroll
    for (int j = 0; j < 8; ++j) {
        float a = acc[j];
        float s = a / (1.f + expf(-a));
        ob[j] = __float2bfloat16(s);
    }
    *(uint4*)(xc_bf + (size_t)v * 8) = *(const uint4*)ob;
}

// ---------------------------------------------------------------------------
// Chunked selective scan, phase 1 (proven body): per (b, chunk, d)
// within-chunk scan from h=0; bf16 delta/u inputs, B/C staged in LDS.
// ---------------------------------------------------------------------------
__global__ __launch_bounds__(256) void scan_part_k(
    const bf16* __restrict__ delta,
    const bf16* __restrict__ xc,
    const float* __restrict__ xdbl,
    const float* __restrict__ A2,
    const float* __restrict__ D_param,
    float* __restrict__ cumdv,
    float* __restrict__ ypart,
    float* __restrict__ hpart)
{
    __shared__ float sBC[CLEN][32];   // [step][B 0..15 | C 16..31]
    const int tid = threadIdx.x;
    const int dgrp  = blockIdx.x % 6;
    const int chunk = (blockIdx.x / 6) & (NCHUNK - 1);
    const int b     = blockIdx.x / (6 * NCHUNK);
    const int d  = dgrp * 256 + tid;
    const int t0 = chunk * CLEN;

    {
        int r = tid >> 5, c = tid & 31;
        sBC[r][c]     = xdbl[(size_t)(b * SEQ + t0 + r) * XPROJ_N + DT_RANK + c];
        sBC[r + 8][c] = xdbl[(size_t)(b * SEQ + t0 + r + 8) * XPROJ_N + DT_RANK + c];
    }

    float a2[16];
    {
        const float4* ap = (const float4*)(A2 + (size_t)d * 16);
        #pragma unroll
        for (int q = 0; q < 4; ++q) {
            float4 vv = ap[q];
            a2[q * 4 + 0] = vv.x; a2[q * 4 + 1] = vv.y;
            a2[q * 4 + 2] = vv.z; a2[q * 4 + 3] = vv.w;
        }
    }
    const float Dp = D_param[d];

    const size_t base = (size_t)(b * SEQ + t0) * D_INNER + d;
    const bf16* dp = delta + base;
    const bf16* up = xc + base;

    float dvv[CLEN], uvv[CLEN];
    #pragma unroll
    for (int s = 0; s < CLEN; ++s) {
        dvv[s] = b2f(dp[(size_t)s * D_INNER]);
        uvv[s] = b2f(up[(size_t)s * D_INNER]);
    }
    __syncthreads();

    float h[16];
    #pragma unroll
    for (int n = 0; n < 16; ++n) h[n] = 0.f;
    float cum = 0.f;

    #pragma unroll
    for (int s = 0; s < CLEN; ++s) {
        float dv = dvv[s], u = uvv[s];
        cum += dv;
        cumdv[base + (size_t)s * D_INNER] = cum;
        float du = dv * u;
        float yv = 0.f;
        #pragma unroll
        for (int n = 0; n < 16; ++n) {
            float dA = exp2f(dv * a2[n]);
            h[n] = fmaf(dA, h[n], du * sBC[s][n]);
            yv = fmaf(h[n], sBC[s][16 + n], yv);
        }
        ypart[base + (size_t)s * D_INNER] = fmaf(u, Dp, yv);
    }

    float4* hp = (float4*)(hpart + (((size_t)b * NCHUNK + chunk) * D_INNER + d) * 16);
    #pragma unroll
    for (int q = 0; q < 4; ++q) {
        float4 vv;
        vv.x = h[q * 4 + 0]; vv.y = h[q * 4 + 1];
        vv.z = h[q * 4 + 2]; vv.w = h[q * 4 + 3];
        hp[q] = vv;
    }
}

// ---------------------------------------------------------------------------
// Phase 2: serial prefix over chunks. Thread = (b,d,n).
// ---------------------------------------------------------------------------
__global__ __launch_bounds__(256) void scan_pref_k(
    const float* __restrict__ cumdv,
    const float* __restrict__ hpart,
    const float* __restrict__ A2,
    float* __restrict__ hinb)
{
    int idx = blockIdx.x * 256 + threadIdx.x;   // < 4*1536*16
    int n = idx & 15;
    int r = idx >> 4;
    int d = r % D_INNER;
    int b = r / D_INNER;
    float a2 = A2[(size_t)d * 16 + n];
    float hin = 0.f;
    #pragma unroll
    for (int c = 0; c < NCHUNK; ++c) {
        hinb[(((size_t)b * NCHUNK + c) * D_INNER + d) * 16 + n] = hin;
        float sdv = cumdv[(size_t)(b * SEQ + c * CLEN + CLEN - 1) * D_INNER + d];
        float hp  = hpart[(((size_t)b * NCHUNK + c) * D_INNER + d) * 16 + n];
        hin = fmaf(hin, exp2f(a2 * sdv), hp);
    }
}

// ---------------------------------------------------------------------------
// Phase 3 (vectorized): one block per token row, 384 thr, 4 d's per thread:
// y = (ypart + sum_n C[n]*exp2(A2[n]*cumdv)*hin[n]) * silu(res)
// ---------------------------------------------------------------------------
__global__ __launch_bounds__(384) void scan_fix_k(
    const float* __restrict__ ypart,
    const float* __restrict__ cumdv,
    const float* __restrict__ xdbl,
    const bf16* __restrict__ xz,
    const float* __restrict__ A2,
    const float* __restrict__ hinb,
    bf16* __restrict__ y)
{
    __shared__ float sC[16];
    const int bt = blockIdx.x;
    const int d0 = threadIdx.x * 4;
    const int t = bt & (SEQ - 1);
    const int b = bt >> 8;
    const int chunk = t >> 4;   // CLEN = 16

    if (threadIdx.x < 16)
        sC[threadIdx.x] = xdbl[(size_t)bt * XPROJ_N + DT_RANK + D_STATE + threadIdx.x];
    __syncthreads();

    const size_t base = (size_t)bt * D_INNER + d0;
    float4 cum = *(const float4*)(cumdv + base);
    float4 yp  = *(const float4*)(ypart + base);
    ushort4 rv = *(const ushort4*)(xz + (size_t)bt * 2 * D_INNER + D_INNER + d0);

    __align__(8) bf16 ob[4];
    #pragma unroll
    for (int j = 0; j < 4; ++j) {
        int d = d0 + j;
        float cu = (j == 0) ? cum.x : (j == 1) ? cum.y : (j == 2) ? cum.z : cum.w;
        float ypj = (j == 0) ? yp.x : (j == 1) ? yp.y : (j == 2) ? yp.z : yp.w;
        unsigned short ru = (j == 0) ? rv.x : (j == 1) ? rv.y : (j == 2) ? rv.z : rv.w;

        const float4* hp = (const float4*)(hinb + (((size_t)b * NCHUNK + chunk) * D_INNER + d) * 16);
        const float4* ap = (const float4*)(A2 + (size_t)d * 16);
        float corr = 0.f;
        #pragma unroll
        for (int q = 0; q < 4; ++q) {
            float4 hv = hp[q];
            float4 av = ap[q];
            corr = fmaf(exp2f(av.x * cu) * hv.x, sC[q * 4 + 0], corr);
            corr = fmaf(exp2f(av.y * cu) * hv.y, sC[q * 4 + 1], corr);
            corr = fmaf(exp2f(av.z * cu) * hv.z, sC[q * 4 + 2], corr);
            corr = fmaf(exp2f(av.w * cu) * hv.w, sC[q * 4 + 3], corr);
        }
        float res = us2f(ru);
        float sr = res / (1.f + expf(-res));
        ob[j] = __float2bfloat16((ypj + corr) * sr);
    }
    *(ushort4*)(y + base) = *(const ushort4*)ob;
}

// ---------------------------------------------------------------------------
// Launch
// ---------------------------------------------------------------------------
extern "C" void kernel_launch(void* const* d_in, const int* in_sizes, int n_in,
                              void* d_out, int out_size, void* d_ws, size_t ws_size,
                              hipStream_t stream)
{
    const float* frames  = (const float*)d_in[0];
    const float* fproj_w = (const float*)d_in[1];
    const float* fproj_b = (const float*)d_in[2];
    const float* norm_w  = (const float*)d_in[3];
    const float* in_w    = (const float*)d_in[4];
    const float* conv_w  = (const float*)d_in[5];
    const float* conv_b  = (const float*)d_in[6];
    const float* xproj_w = (const float*)d_in[7];
    const float* dt_w    = (const float*)d_in[8];
    const float* dt_b    = (const float*)d_in[9];
    const float* A_log   = (const float*)d_in[10];
    const float* D_param = (const float*)d_in[11];
    const float* out_w   = (const float*)d_in[12];
    const float* normf_w = (const float*)d_in[13];

    // workspace layout
    char* ws = (char*)d_ws;
    float* h      = (float*)ws;        ws += (size_t)M_TOK * D_MODEL * 4;
    float* xdbl   = (float*)ws;        ws += (size_t)M_TOK * XPROJ_N * 4;
    float* part   = (float*)ws;        ws += (size_t)KSPLIT * M_TOK * XPROJ_N * 4;
    float* cumdv  = (float*)ws;        ws += (size_t)M_TOK * D_INNER * 4;
    float* ypartb = (float*)ws;        ws += (size_t)M_TOK * D_INNER * 4;
    float* hpartb = (float*)ws;        ws += (size_t)BATCH * NCHUNK * D_INNER * 16 * 4;
    float* hinb   = (float*)ws;        ws += (size_t)BATCH * NCHUNK * D_INNER * 16 * 4;
    float* A2all  = (float*)ws;        ws += (size_t)N_LAYER * D_INNER * 16 * 4;
    bf16* xz_bf   = (bf16*)ws;         ws += (size_t)M_TOK * 2 * D_INNER * 2;
    bf16* xc_bf   = (bf16*)ws;         ws += (size_t)M_TOK * D_INNER * 2;
    bf16* delta_bf= (bf16*)ws;         ws += (size_t)M_TOK * D_INNER * 2;
    bf16* x_bf    = (bf16*)ws;         ws += (size_t)M_TOK * D_MODEL * 2;
    bf16* y_bf    = (bf16*)ws;         ws += (size_t)M_TOK * D_INNER * 2;
    bf16* fr_bf   = (bf16*)ws;         ws += (size_t)M_TOK * IMG_DIM * 2;
    bf16* fp_wT   = (bf16*)ws;         ws += (size_t)D_MODEL * IMG_DIM * 2;
    bf16* in_wT   = (bf16*)ws;         ws += (size_t)N_LAYER * 2 * D_INNER * D_MODEL * 2;
    bf16* out_wT  = (bf16*)ws;         ws += (size_t)N_LAYER * D_MODEL * D_INNER * 2;
    bf16* xprojT  = (bf16*)ws;         ws += (size_t)N_LAYER * XPROJ_N * D_INNER * 2;
    bf16* dt_wT   = (bf16*)ws;         ws += (size_t)N_LAYER * D_INNER * 64 * 2;

    dim3 blk(256);

    // --- once-per-call preprocessing (batched over all layers) ---
    cvt_bf16_k<<<(M_TOK * IMG_DIM) / 256, blk, 0, stream>>>(
        frames, fr_bf, M_TOK * IMG_DIM);
    wcvt_t_k<<<dim3(D_MODEL / 32, IMG_DIM / 32, 1), blk, 0, stream>>>(
        fproj_w, fp_wT, IMG_DIM, D_MODEL);
    wcvt_t_k<<<dim3(2 * D_INNER / 32, D_MODEL / 32, N_LAYER), blk, 0, stream>>>(
        in_w, in_wT, D_MODEL, 2 * D_INNER);
    wcvt_t_k<<<dim3(D_MODEL / 32, D_INNER / 32, N_LAYER), blk, 0, stream>>>(
        out_w, out_wT, D_INNER, D_MODEL);
    wcvt_t_k<<<dim3((XPROJ_N + 31) / 32, D_INNER / 32, N_LAYER), blk, 0, stream>>>(
        xproj_w, xprojT, D_INNER, XPROJ_N);
    dtw_cvt_k<<<(N_LAYER * D_INNER * 64) / 256, blk, 0, stream>>>(dt_w, dt_wT);
    a2_k<<<(N_LAYER * D_INNER * 16) / 256, blk, 0, stream>>>(A_log, A2all);

    // h = relu(frames @ fproj_w + fproj_b)
    gemm_bf16<1, float><<<dim3(M_TOK / 64, D_MODEL / 64), blk, 0, stream>>>(
        fr_bf, fp_wT, h, D_MODEL, IMG_DIM, fproj_b);

    for (int i = 0; i < N_LAYER; ++i) {
        const bf16* in_wTi   = in_wT  + (size_t)i * 2 * D_INNER * D_MODEL;
        const bf16* out_wTi  = out_wT + (size_t)i * D_MODEL * D_INNER;
        const bf16* xprojTi  = xprojT + (size_t)i * XPROJ_N * D_INNER;
        const bf16* dt_wTi   = dt_wT  + (size_t)i * D_INNER * 64;
        const float* A2i     = A2all  + (size_t)i * D_INNER * 16;
        const float* conv_wi = conv_w + (size_t)i * D_INNER * D_CONV;
        const float* conv_bi = conv_b + (size_t)i * D_INNER;
        const float* dt_bi   = dt_b   + (size_t)i * D_INNER;
        const float* D_parami= D_param+ (size_t)i * D_INNER;
        const float* norm_wi = norm_w + (size_t)i * D_MODEL;

        rmsnorm_k<bf16><<<M_TOK, blk, 0, stream>>>(h, norm_wi, x_bf);
        gemm_bf16<0, bf16><<<dim3(M_TOK / 64, (2 * D_INNER) / 64), blk, 0, stream>>>(
            x_bf, in_wTi, xz_bf, 2 * D_INNER, D_MODEL, nullptr);
        conv_silu_k<<<(M_TOK * D_INNER / 8) / 256, blk, 0, stream>>>(
            xz_bf, conv_wi, conv_bi, xc_bf);
        xproj_gemm_k<<<dim3(M_TOK / 64, KSPLIT), blk, 0, stream>>>(
            xc_bf, xprojTi, part);
        xred_dt_k<<<dim3(M_TOK / 64, D_INNER / 64), blk, 0, stream>>>(
            part, dt_wTi, dt_bi, xdbl, delta_bf);
        scan_part_k<<<BATCH * NCHUNK * (D_INNER / 256), blk, 0, stream>>>(
            delta_bf, xc_bf, xdbl, A2i, D_parami, cumdv, ypartb, hpartb);
        scan_pref_k<<<(BATCH * D_INNER * 16) / 256, blk, 0, stream>>>(
            cumdv, hpartb, A2i, hinb);
        scan_fix_k<<<M_TOK, dim3(384), 0, stream>>>(
            ypartb, cumdv, xdbl, xz_bf, A2i, hinb, y_bf);
        gemm_bf16<3, float><<<dim3(M_TOK / 64, D_MODEL / 64), blk, 0, stream>>>(
            y_bf, out_wTi, h, D_MODEL, D_INNER, nullptr);
    }

    // out = rmsnorm(h, normf_w)  (fp32)
    rmsnorm_k<float><<<M_TOK, blk, 0, stream>>>(h, normf_w, (float*)d_out);
}

// Round 13
// 1282.033 us; speedup vs baseline: 1.2396x; 1.2396x over previous
//
#include <hip/hip_runtime.h>
#include <hip/hip_bf16.h>
#include <cmath>

#define IMG_DIM 512
#define D_MODEL 768
#define N_LAYER 12
#define D_INNER 1536
#define D_STATE 16
#define D_CONV 4
#define DT_RANK 48
#define BATCH 4
#define SEQ 256
#define M_TOK (BATCH * SEQ)               // 1024 token rows
#define XPROJ_N (DT_RANK + 2 * D_STATE)   // 80
#define KSPLIT 16
#define NCHUNK 16
#define CLEN 16                           // SEQ / NCHUNK
#define LOG2E 1.4426950408889634f

typedef __attribute__((ext_vector_type(8))) short bf16x8;
typedef __attribute__((ext_vector_type(8))) unsigned short u16x8;
typedef __attribute__((ext_vector_type(4))) float f32x4;
typedef __hip_bfloat16 bf16;

__device__ __forceinline__ float softplus_f(float v) {
    return v > 20.f ? v : log1pf(expf(v));
}
__device__ __forceinline__ float b2f(bf16 v) { return __bfloat162float(v); }
__device__ __forceinline__ float us2f(unsigned short v) {
    return __uint_as_float(((unsigned)v) << 16);
}

// async global->LDS, 16B per lane; LDS dest is wave-uniform base + lane*16
__device__ __forceinline__ void gl_lds16(const char* g, char* l) {
    __builtin_amdgcn_global_load_lds(
        (const __attribute__((address_space(1))) unsigned int*)g,
        (__attribute__((address_space(3))) unsigned int*)l,
        16, 0, 0);
}

// ---------------------------------------------------------------------------
// Weight transpose + fp32->bf16: W[z][K][N] -> WT[z][N][K]; N-guarded.
// ---------------------------------------------------------------------------
__global__ __launch_bounds__(256) void wcvt_t_k(
    const float* __restrict__ W, bf16* __restrict__ WT, int K, int N)
{
    __shared__ float tile[32][33];
    W  += (size_t)blockIdx.z * K * N;
    WT += (size_t)blockIdx.z * K * N;
    const int tx = threadIdx.x & 31;
    const int ty4 = (threadIdx.x >> 5) * 4;
    const int n0 = blockIdx.x * 32, k0 = blockIdx.y * 32;
    #pragma unroll
    for (int r = 0; r < 4; ++r)
        tile[ty4 + r][tx] = (n0 + tx < N)
            ? W[(size_t)(k0 + ty4 + r) * N + n0 + tx] : 0.f;
    __syncthreads();
    #pragma unroll
    for (int r = 0; r < 4; ++r)
        if (n0 + ty4 + r < N)
            WT[(size_t)(n0 + ty4 + r) * K + k0 + tx] =
                __float2bfloat16(tile[tx][ty4 + r]);
}

// ---------------------------------------------------------------------------
// Flat fp32 -> bf16 convert
// ---------------------------------------------------------------------------
__global__ __launch_bounds__(256) void cvt_bf16_k(
    const float* __restrict__ in, bf16* __restrict__ out, int n)
{
    int i = blockIdx.x * 256 + threadIdx.x;
    if (i < n) out[i] = __float2bfloat16(in[i]);
}

// ---------------------------------------------------------------------------
// dt_w (all layers) [12][48][1536] -> dt_wT [12][1536][64], zero-pad k 48..63
// ---------------------------------------------------------------------------
__global__ __launch_bounds__(256) void dtw_cvt_k(
    const float* __restrict__ dt_w, bf16* __restrict__ dtwT)
{
    int idx = blockIdx.x * 256 + threadIdx.x;   // over 12*1536*64
    int k = idx & 63;
    int n = (idx >> 6) % D_INNER;
    int l = idx / (64 * D_INNER);
    dtwT[idx] = (k < DT_RANK)
        ? __float2bfloat16(dt_w[((size_t)l * DT_RANK + k) * D_INNER + n])
        : bf16(0.f);
}

// ---------------------------------------------------------------------------
// A2 (all layers): A2[l][d][n] = -exp(A_log[l][d][n]) * log2(e)
// ---------------------------------------------------------------------------
__global__ __launch_bounds__(256) void a2_k(
    const float* __restrict__ A_log, float* __restrict__ A2)
{
    int idx = blockIdx.x * 256 + threadIdx.x;   // < 12*1536*16
    A2[idx] = -expf(A_log[idx]) * LOG2E;
}

// ---------------------------------------------------------------------------
// bf16 MFMA GEMM, 64x64 tile (4 waves 2x2) — proven R10 body.
// EPI: 0 = store, 1 = bias+relu, 2 = bias+softplus, 3 = accumulate
// ---------------------------------------------------------------------------
template <int EPI, typename OT>
__global__ __launch_bounds__(256) void gemm_bf16(
    const bf16* __restrict__ A,
    const bf16* __restrict__ BT,
    OT* __restrict__ C, int ldc, int K,
    const float* __restrict__ bias)
{
    __shared__ __align__(16) char lds[2][16384];   // [buf][A 8K | B 8K]
    const int tid = threadIdx.x;
    const int lane = tid & 63;
    const int wid = tid >> 6;
    const int wr = wid >> 1, wc = wid & 1;
    const size_t rowBase = blockIdx.x * 64;
    const size_t colBase = blockIdx.y * 64;

    const int r0 = tid >> 3;
    const int cb0 = (tid & 7) * 16;
    const int slot = tid * 16;
    const size_t gOffSw = (size_t)r0 * K * 2 + (cb0 ^ ((r0 & 7) << 4));
    const size_t aStep = (size_t)32 * K * 2;   // +32 rows
    const char* gA = (const char*)(A + rowBase * K);
    const char* gB = (const char*)(BT + colBase * K);

    const int lrow = lane & 15;
    const int kg = (lane >> 4) * 16;
    const int swz = (lane & 7) << 4;

    f32x4 acc[2][2] = {};
    const int nt = K >> 6;

    {
        char* L = &lds[0][0];
        gl_lds16(gA + gOffSw,          L + slot);
        gl_lds16(gA + gOffSw + aStep,  L + 4096 + slot);
        gl_lds16(gB + gOffSw,          L + 8192 + slot);
        gl_lds16(gB + gOffSw + aStep,  L + 12288 + slot);
    }
    __syncthreads();

    for (int t = 0; t < nt; ++t) {
        const int cur = t & 1;
        if (t + 1 < nt) {
            char* L = &lds[cur ^ 1][0];
            size_t go = gOffSw + (size_t)(t + 1) * 128;
            gl_lds16(gA + go,          L + slot);
            gl_lds16(gA + go + aStep,  L + 4096 + slot);
            gl_lds16(gB + go,          L + 8192 + slot);
            gl_lds16(gB + go + aStep,  L + 12288 + slot);
        }
        #pragma unroll
        for (int kk = 0; kk < 2; ++kk) {
            const int col = (kk * 64 + kg) ^ swz;
            bf16x8 a0 = *(const bf16x8*)(&lds[cur][(wr * 32 +      lrow) * 128 + col]);
            bf16x8 a1 = *(const bf16x8*)(&lds[cur][(wr * 32 + 16 + lrow) * 128 + col]);
            bf16x8 b0 = *(const bf16x8*)(&lds[cur][8192 + (wc * 32 +      lrow) * 128 + col]);
            bf16x8 b1 = *(const bf16x8*)(&lds[cur][8192 + (wc * 32 + 16 + lrow) * 128 + col]);
            acc[0][0] = __builtin_amdgcn_mfma_f32_16x16x32_bf16(a0, b0, acc[0][0], 0, 0, 0);
            acc[0][1] = __builtin_amdgcn_mfma_f32_16x16x32_bf16(a0, b1, acc[0][1], 0, 0, 0);
            acc[1][0] = __builtin_amdgcn_mfma_f32_16x16x32_bf16(a1, b0, acc[1][0], 0, 0, 0);
            acc[1][1] = __builtin_amdgcn_mfma_f32_16x16x32_bf16(a1, b1, acc[1][1], 0, 0, 0);
        }
        __syncthreads();
    }

    const int mBase = (int)rowBase + wr * 32 + (lane >> 4) * 4;
    const int nBase = (int)colBase + wc * 32 + (lane & 15);
    #pragma unroll
    for (int i = 0; i < 2; ++i)
        #pragma unroll
        for (int j = 0; j < 2; ++j)
            #pragma unroll
            for (int rg = 0; rg < 4; ++rg) {
                int cc = nBase + j * 16;
                size_t idx = (size_t)(mBase + i * 16 + rg) * ldc + cc;
                float v = acc[i][j][rg];
                if (EPI == 0) {
                    C[idx] = (OT)v;
                } else if (EPI == 1) {
                    v += bias[cc];
                    C[idx] = (OT)(v > 0.f ? v : 0.f);
                } else if (EPI == 2) {
                    v += bias[cc];
                    C[idx] = (OT)softplus_f(v);
                } else {
                    C[idx] += v;
                }
            }
}

// ---------------------------------------------------------------------------
// Skinny split-K MFMA GEMM for xproj (no LDS); KSPLIT=16 -> 256 blocks
// ---------------------------------------------------------------------------
__global__ __launch_bounds__(256) void xproj_gemm_k(
    const bf16* __restrict__ xc_bf,
    const bf16* __restrict__ xprojT,
    float* __restrict__ part)
{
    const int lane = threadIdx.x & 63;
    const int w = threadIdx.x >> 6;
    const int m0 = blockIdx.x * 64 + w * 16;
    const int ks = blockIdx.y;
    const int KS = D_INNER / KSPLIT;          // 96
    const int k0 = ks * KS;

    const int arow = m0 + (lane & 15);
    const int kgrp = (lane >> 4) * 8;

    f32x4 acc[5] = {};
    const bf16* ap = xc_bf + (size_t)arow * D_INNER + kgrp;
    const bf16* bp = xprojT + (size_t)(lane & 15) * D_INNER + kgrp;

    for (int k = k0; k < k0 + KS; k += 32) {
        bf16x8 a = *(const bf16x8*)(ap + k);
        #pragma unroll
        for (int f = 0; f < 5; ++f) {
            bf16x8 b = *(const bf16x8*)(bp + (size_t)f * 16 * D_INNER + k);
            acc[f] = __builtin_amdgcn_mfma_f32_16x16x32_bf16(a, b, acc[f], 0, 0, 0);
        }
    }

    float* out = part + (size_t)ks * M_TOK * XPROJ_N;
    const int rowb = blockIdx.x * 64 + w * 16 + (lane >> 4) * 4;
    #pragma unroll
    for (int f = 0; f < 5; ++f)
        #pragma unroll
        for (int rg = 0; rg < 4; ++rg)
            out[(size_t)(rowb + rg) * XPROJ_N + f * 16 + (lane & 15)] = acc[f][rg];
}

// ---------------------------------------------------------------------------
// Reduce split-K partials -> xdbl fp32 [1024][80]; cols<48 also -> dtin bf16.
// Threads with col in [64,80) additionally zero dtin pad cols 48..63
// (replaces the once-per-call memset dispatch).
// ---------------------------------------------------------------------------
__global__ __launch_bounds__(256) void xproj_reduce_k(
    const float* __restrict__ part, float* __restrict__ xdbl,
    bf16* __restrict__ dtin)
{
    int idx = blockIdx.x * 256 + threadIdx.x;   // < 1024*80
    float s = 0.f;
    #pragma unroll
    for (int p = 0; p < KSPLIT; ++p)
        s += part[(size_t)p * M_TOK * XPROJ_N + idx];
    xdbl[idx] = s;
    int col = idx % XPROJ_N;
    int row = idx / XPROJ_N;
    if (col < DT_RANK)
        dtin[(size_t)row * 64 + col] = __float2bfloat16(s);
    else if (col >= 64)
        dtin[(size_t)row * 64 + col - 16] = bf16(0.f);
}

// ---------------------------------------------------------------------------
// RMSNorm: one block per token row; templated output type
// ---------------------------------------------------------------------------
template <typename OT>
__global__ __launch_bounds__(256) void rmsnorm_k(
    const float* __restrict__ x, const float* __restrict__ w,
    OT* __restrict__ o)
{
    const int row = blockIdx.x;
    const float* xr = x + (size_t)row * D_MODEL;
    float v[3];
    float s = 0.f;
    #pragma unroll
    for (int i = 0; i < 3; ++i) {
        v[i] = xr[threadIdx.x + i * 256];
        s = fmaf(v[i], v[i], s);
    }
    #pragma unroll
    for (int off = 32; off > 0; off >>= 1) s += __shfl_down(s, off);
    __shared__ float red[4];
    if ((threadIdx.x & 63) == 0) red[threadIdx.x >> 6] = s;
    __syncthreads();
    float tot = red[0] + red[1] + red[2] + red[3];
    float r = rsqrtf(tot * (1.f / D_MODEL) + 1e-5f);
    OT* orow = o + (size_t)row * D_MODEL;
    #pragma unroll
    for (int i = 0; i < 3; ++i) {
        int c = threadIdx.x + i * 256;
        orow[c] = (OT)(v[i] * r * w[c]);
    }
}

// ---------------------------------------------------------------------------
// Causal depthwise conv (width 4) + bias + silu; vectorized 8 d / thread
// ---------------------------------------------------------------------------
__global__ __launch_bounds__(256) void conv_silu_k(
    const bf16* __restrict__ xz, const float* __restrict__ cw,
    const float* __restrict__ cb, bf16* __restrict__ xc_bf)
{
    int v = blockIdx.x * 256 + threadIdx.x;   // over M_TOK*D_INNER/8
    int d8 = (v * 8) % D_INNER;
    int bt = (v * 8) / D_INNER;
    int t = bt & (SEQ - 1);
    int b = bt >> 8;

    float acc[8];
    {
        const float4* cbp = (const float4*)(cb + d8);
        float4 c0 = cbp[0], c1 = cbp[1];
        acc[0] = c0.x; acc[1] = c0.y; acc[2] = c0.z; acc[3] = c0.w;
        acc[4] = c1.x; acc[5] = c1.y; acc[6] = c1.z; acc[7] = c1.w;
    }
    float4 wv[8];
    #pragma unroll
    for (int j = 0; j < 8; ++j)
        wv[j] = *(const float4*)(cw + (size_t)(d8 + j) * 4);

    #pragma unroll
    for (int k = 0; k < 4; ++k) {
        int tt = t - 3 + k;
        if (tt >= 0) {
            u16x8 xv = *(const u16x8*)(xz + (size_t)(b * SEQ + tt) * (2 * D_INNER) + d8);
            #pragma unroll
            for (int j = 0; j < 8; ++j) {
                float wk = (k == 0) ? wv[j].x : (k == 1) ? wv[j].y
                         : (k == 2) ? wv[j].z : wv[j].w;
                acc[j] = fmaf(us2f(xv[j]), wk, acc[j]);
            }
        }
    }

    __align__(16) bf16 ob[8];
    #pragma unroll
    for (int j = 0; j < 8; ++j) {
        float a = acc[j];
        float s = a / (1.f + expf(-a));
        ob[j] = __float2bfloat16(s);
    }
    *(uint4*)(xc_bf + (size_t)v * 8) = *(const uint4*)ob;
}

// ---------------------------------------------------------------------------
// Chunked selective scan, phase 1 (proven body): per (b, chunk, d)
// within-chunk scan from h=0; bf16 delta/u inputs, B/C staged in LDS.
// ---------------------------------------------------------------------------
__global__ __launch_bounds__(256) void scan_part_k(
    const bf16* __restrict__ delta,
    const bf16* __restrict__ xc,
    const float* __restrict__ xdbl,
    const float* __restrict__ A2,
    const float* __restrict__ D_param,
    float* __restrict__ cumdv,
    float* __restrict__ ypart,
    float* __restrict__ hpart)
{
    __shared__ float sBC[CLEN][32];   // [step][B 0..15 | C 16..31]
    const int tid = threadIdx.x;
    const int dgrp  = blockIdx.x % 6;
    const int chunk = (blockIdx.x / 6) & (NCHUNK - 1);
    const int b     = blockIdx.x / (6 * NCHUNK);
    const int d  = dgrp * 256 + tid;
    const int t0 = chunk * CLEN;

    {
        int r = tid >> 5, c = tid & 31;
        sBC[r][c]     = xdbl[(size_t)(b * SEQ + t0 + r) * XPROJ_N + DT_RANK + c];
        sBC[r + 8][c] = xdbl[(size_t)(b * SEQ + t0 + r + 8) * XPROJ_N + DT_RANK + c];
    }

    float a2[16];
    {
        const float4* ap = (const float4*)(A2 + (size_t)d * 16);
        #pragma unroll
        for (int q = 0; q < 4; ++q) {
            float4 vv = ap[q];
            a2[q * 4 + 0] = vv.x; a2[q * 4 + 1] = vv.y;
            a2[q * 4 + 2] = vv.z; a2[q * 4 + 3] = vv.w;
        }
    }
    const float Dp = D_param[d];

    const size_t base = (size_t)(b * SEQ + t0) * D_INNER + d;
    const bf16* dp = delta + base;
    const bf16* up = xc + base;

    float dvv[CLEN], uvv[CLEN];
    #pragma unroll
    for (int s = 0; s < CLEN; ++s) {
        dvv[s] = b2f(dp[(size_t)s * D_INNER]);
        uvv[s] = b2f(up[(size_t)s * D_INNER]);
    }
    __syncthreads();

    float h[16];
    #pragma unroll
    for (int n = 0; n < 16; ++n) h[n] = 0.f;
    float cum = 0.f;

    #pragma unroll
    for (int s = 0; s < CLEN; ++s) {
        float dv = dvv[s], u = uvv[s];
        cum += dv;
        cumdv[base + (size_t)s * D_INNER] = cum;
        float du = dv * u;
        float yv = 0.f;
        #pragma unroll
        for (int n = 0; n < 16; ++n) {
            float dA = exp2f(dv * a2[n]);
            h[n] = fmaf(dA, h[n], du * sBC[s][n]);
            yv = fmaf(h[n], sBC[s][16 + n], yv);
        }
        ypart[base + (size_t)s * D_INNER] = fmaf(u, Dp, yv);
    }

    float4* hp = (float4*)(hpart + (((size_t)b * NCHUNK + chunk) * D_INNER + d) * 16);
    #pragma unroll
    for (int q = 0; q < 4; ++q) {
        float4 vv;
        vv.x = h[q * 4 + 0]; vv.y = h[q * 4 + 1];
        vv.z = h[q * 4 + 2]; vv.w = h[q * 4 + 3];
        hp[q] = vv;
    }
}

// ---------------------------------------------------------------------------
// Phase 2: serial prefix over chunks. Thread = (b,d,n).
// ---------------------------------------------------------------------------
__global__ __launch_bounds__(256) void scan_pref_k(
    const float* __restrict__ cumdv,
    const float* __restrict__ hpart,
    const float* __restrict__ A2,
    float* __restrict__ hinb)
{
    int idx = blockIdx.x * 256 + threadIdx.x;   // < 4*1536*16
    int n = idx & 15;
    int r = idx >> 4;
    int d = r % D_INNER;
    int b = r / D_INNER;
    float a2 = A2[(size_t)d * 16 + n];
    float hin = 0.f;
    #pragma unroll
    for (int c = 0; c < NCHUNK; ++c) {
        hinb[(((size_t)b * NCHUNK + c) * D_INNER + d) * 16 + n] = hin;
        float sdv = cumdv[(size_t)(b * SEQ + c * CLEN + CLEN - 1) * D_INNER + d];
        float hp  = hpart[(((size_t)b * NCHUNK + c) * D_INNER + d) * 16 + n];
        hin = fmaf(hin, exp2f(a2 * sdv), hp);
    }
}

// ---------------------------------------------------------------------------
// Phase 3: elementwise fix-up (proven R10 body):
// y = (ypart + sum_n C[n]*exp2(A2[n]*cumdv)*hin[n]) * silu(res)
// ---------------------------------------------------------------------------
__global__ __launch_bounds__(256) void scan_fix_k(
    const float* __restrict__ ypart,
    const float* __restrict__ cumdv,
    const float* __restrict__ xdbl,
    const bf16* __restrict__ xz,
    const float* __restrict__ A2,
    const float* __restrict__ hinb,
    bf16* __restrict__ y)
{
    __shared__ float sC[16];
    int idx = blockIdx.x * 256 + threadIdx.x;   // bt constant per block
    int d = idx % D_INNER;
    int bt = idx / D_INNER;
    int t = bt & (SEQ - 1);
    int b = bt >> 8;
    int chunk = t >> 4;   // CLEN = 16

    if (threadIdx.x < 16)
        sC[threadIdx.x] = xdbl[(size_t)bt * XPROJ_N + DT_RANK + D_STATE + threadIdx.x];
    __syncthreads();

    float cum = cumdv[idx];
    float yp  = ypart[idx];
    float res = b2f(xz[(size_t)bt * 2 * D_INNER + D_INNER + d]);

    const float4* hp = (const float4*)(hinb + (((size_t)b * NCHUNK + chunk) * D_INNER + d) * 16);
    const float4* ap = (const float4*)(A2 + (size_t)d * 16);

    float corr = 0.f;
    #pragma unroll
    for (int q = 0; q < 4; ++q) {
        float4 hv = hp[q];
        float4 av = ap[q];
        corr = fmaf(exp2f(av.x * cum) * hv.x, sC[q * 4 + 0], corr);
        corr = fmaf(exp2f(av.y * cum) * hv.y, sC[q * 4 + 1], corr);
        corr = fmaf(exp2f(av.z * cum) * hv.z, sC[q * 4 + 2], corr);
        corr = fmaf(exp2f(av.w * cum) * hv.w, sC[q * 4 + 3], corr);
    }
    float sr = res / (1.f + expf(-res));
    y[idx] = __float2bfloat16((yp + corr) * sr);
}

// ---------------------------------------------------------------------------
// Launch
// ---------------------------------------------------------------------------
extern "C" void kernel_launch(void* const* d_in, const int* in_sizes, int n_in,
                              void* d_out, int out_size, void* d_ws, size_t ws_size,
                              hipStream_t stream)
{
    const float* frames  = (const float*)d_in[0];
    const float* fproj_w = (const float*)d_in[1];
    const float* fproj_b = (const float*)d_in[2];
    const float* norm_w  = (const float*)d_in[3];
    const float* in_w    = (const float*)d_in[4];
    const float* conv_w  = (const float*)d_in[5];
    const float* conv_b  = (const float*)d_in[6];
    const float* xproj_w = (const float*)d_in[7];
    const float* dt_w    = (const float*)d_in[8];
    const float* dt_b    = (const float*)d_in[9];
    const float* A_log   = (const float*)d_in[10];
    const float* D_param = (const float*)d_in[11];
    const float* out_w   = (const float*)d_in[12];
    const float* normf_w = (const float*)d_in[13];

    // workspace layout
    char* ws = (char*)d_ws;
    float* h      = (float*)ws;        ws += (size_t)M_TOK * D_MODEL * 4;
    float* xdbl   = (float*)ws;        ws += (size_t)M_TOK * XPROJ_N * 4;
    float* part   = (float*)ws;        ws += (size_t)KSPLIT * M_TOK * XPROJ_N * 4;
    float* cumdv  = (float*)ws;        ws += (size_t)M_TOK * D_INNER * 4;
    float* ypartb = (float*)ws;        ws += (size_t)M_TOK * D_INNER * 4;
    float* hpartb = (float*)ws;        ws += (size_t)BATCH * NCHUNK * D_INNER * 16 * 4;
    float* hinb   = (float*)ws;        ws += (size_t)BATCH * NCHUNK * D_INNER * 16 * 4;
    float* A2all  = (float*)ws;        ws += (size_t)N_LAYER * D_INNER * 16 * 4;
    bf16* xz_bf   = (bf16*)ws;         ws += (size_t)M_TOK * 2 * D_INNER * 2;
    bf16* xc_bf   = (bf16*)ws;         ws += (size_t)M_TOK * D_INNER * 2;
    bf16* delta_bf= (bf16*)ws;         ws += (size_t)M_TOK * D_INNER * 2;
    bf16* x_bf    = (bf16*)ws;         ws += (size_t)M_TOK * D_MODEL * 2;
    bf16* y_bf    = (bf16*)ws;         ws += (size_t)M_TOK * D_INNER * 2;
    bf16* dtin    = (bf16*)ws;         ws += (size_t)M_TOK * 64 * 2;
    bf16* fr_bf   = (bf16*)ws;         ws += (size_t)M_TOK * IMG_DIM * 2;
    bf16* fp_wT   = (bf16*)ws;         ws += (size_t)D_MODEL * IMG_DIM * 2;
    bf16* in_wT   = (bf16*)ws;         ws += (size_t)N_LAYER * 2 * D_INNER * D_MODEL * 2;
    bf16* out_wT  = (bf16*)ws;         ws += (size_t)N_LAYER * D_MODEL * D_INNER * 2;
    bf16* xprojT  = (bf16*)ws;         ws += (size_t)N_LAYER * XPROJ_N * D_INNER * 2;
    bf16* dt_wT   = (bf16*)ws;         ws += (size_t)N_LAYER * D_INNER * 64 * 2;

    dim3 blk(256);

    // --- once-per-call preprocessing (batched over all layers) ---
    cvt_bf16_k<<<(M_TOK * IMG_DIM) / 256, blk, 0, stream>>>(
        frames, fr_bf, M_TOK * IMG_DIM);
    wcvt_t_k<<<dim3(D_MODEL / 32, IMG_DIM / 32, 1), blk, 0, stream>>>(
        fproj_w, fp_wT, IMG_DIM, D_MODEL);
    wcvt_t_k<<<dim3(2 * D_INNER / 32, D_MODEL / 32, N_LAYER), blk, 0, stream>>>(
        in_w, in_wT, D_MODEL, 2 * D_INNER);
    wcvt_t_k<<<dim3(D_MODEL / 32, D_INNER / 32, N_LAYER), blk, 0, stream>>>(
        out_w, out_wT, D_INNER, D_MODEL);
    wcvt_t_k<<<dim3((XPROJ_N + 31) / 32, D_INNER / 32, N_LAYER), blk, 0, stream>>>(
        xproj_w, xprojT, D_INNER, XPROJ_N);
    dtw_cvt_k<<<(N_LAYER * D_INNER * 64) / 256, blk, 0, stream>>>(dt_w, dt_wT);
    a2_k<<<(N_LAYER * D_INNER * 16) / 256, blk, 0, stream>>>(A_log, A2all);

    // h = relu(frames @ fproj_w + fproj_b)
    gemm_bf16<1, float><<<dim3(M_TOK / 64, D_MODEL / 64), blk, 0, stream>>>(
        fr_bf, fp_wT, h, D_MODEL, IMG_DIM, fproj_b);

    for (int i = 0; i < N_LAYER; ++i) {
        const bf16* in_wTi   = in_wT  + (size_t)i * 2 * D_INNER * D_MODEL;
        const bf16* out_wTi  = out_wT + (size_t)i * D_MODEL * D_INNER;
        const bf16* xprojTi  = xprojT + (size_t)i * XPROJ_N * D_INNER;
        const bf16* dt_wTi   = dt_wT  + (size_t)i * D_INNER * 64;
        const float* A2i     = A2all  + (size_t)i * D_INNER * 16;
        const float* conv_wi = conv_w + (size_t)i * D_INNER * D_CONV;
        const float* conv_bi = conv_b + (size_t)i * D_INNER;
        const float* dt_bi   = dt_b   + (size_t)i * D_INNER;
        const float* D_parami= D_param+ (size_t)i * D_INNER;
        const float* norm_wi = norm_w + (size_t)i * D_MODEL;

        rmsnorm_k<bf16><<<M_TOK, blk, 0, stream>>>(h, norm_wi, x_bf);
        gemm_bf16<0, bf16><<<dim3(M_TOK / 64, (2 * D_INNER) / 64), blk, 0, stream>>>(
            x_bf, in_wTi, xz_bf, 2 * D_INNER, D_MODEL, nullptr);
        conv_silu_k<<<(M_TOK * D_INNER / 8) / 256, blk, 0, stream>>>(
            xz_bf, conv_wi, conv_bi, xc_bf);
        xproj_gemm_k<<<dim3(M_TOK / 64, KSPLIT), blk, 0, stream>>>(
            xc_bf, xprojTi, part);
        xproj_reduce_k<<<(M_TOK * XPROJ_N) / 256, blk, 0, stream>>>(
            part, xdbl, dtin);
        gemm_bf16<2, bf16><<<dim3(M_TOK / 64, D_INNER / 64), blk, 0, stream>>>(
            dtin, dt_wTi, delta_bf, D_INNER, 64, dt_bi);
        scan_part_k<<<BATCH * NCHUNK * (D_INNER / 256), blk, 0, stream>>>(
            delta_bf, xc_bf, xdbl, A2i, D_parami, cumdv, ypartb, hpartb);
        scan_pref_k<<<(BATCH * D_INNER * 16) / 256, blk, 0, stream>>>(
            cumdv, hpartb, A2i, hinb);
        scan_fix_k<<<(M_TOK * D_INNER) / 256, blk, 0, stream>>>(
            ypartb, cumdv, xdbl, xz_bf, A2i, hinb, y_bf);
        gemm_bf16<3, float><<<dim3(M_TOK / 64, D_MODEL / 64), blk, 0, stream>>>(
            y_bf, out_wTi, h, D_MODEL, D_INNER, nullptr);
    }

    // out = rmsnorm(h, normf_w)  (fp32)
    rmsnorm_k<float><<<M_TOK, blk, 0, stream>>>(h, normf_w, (float*)d_out);
}

// Round 14
// 1164.960 us; speedup vs baseline: 1.3642x; 1.1005x over previous
//
#include <hip/hip_runtime.h>
#include <hip/hip_bf16.h>
#include <cmath>

#define IMG_DIM 512
#define D_MODEL 768
#define N_LAYER 12
#define D_INNER 1536
#define D_STATE 16
#define D_CONV 4
#define DT_RANK 48
#define BATCH 4
#define SEQ 256
#define M_TOK (BATCH * SEQ)               // 1024 token rows
#define XPROJ_N (DT_RANK + 2 * D_STATE)   // 80
#define KSPLIT 16
#define NCHUNK 16
#define CLEN 16                           // SEQ / NCHUNK
#define LOG2E 1.4426950408889634f

typedef __attribute__((ext_vector_type(8))) short bf16x8;
typedef __attribute__((ext_vector_type(8))) unsigned short u16x8;
typedef __attribute__((ext_vector_type(4))) float f32x4;
typedef __hip_bfloat16 bf16;

__device__ __forceinline__ float softplus_f(float v) {
    return v > 20.f ? v : log1pf(expf(v));
}
__device__ __forceinline__ float b2f(bf16 v) { return __bfloat162float(v); }
__device__ __forceinline__ float us2f(unsigned short v) {
    return __uint_as_float(((unsigned)v) << 16);
}

// async global->LDS, 16B per lane; LDS dest is wave-uniform base + lane*16
__device__ __forceinline__ void gl_lds16(const char* g, char* l) {
    __builtin_amdgcn_global_load_lds(
        (const __attribute__((address_space(1))) unsigned int*)g,
        (__attribute__((address_space(3))) unsigned int*)l,
        16, 0, 0);
}

// ---------------------------------------------------------------------------
// Weight transpose + fp32->bf16: W[z][K][N] -> WT[z][N][K]; N-guarded.
// ---------------------------------------------------------------------------
__global__ __launch_bounds__(256) void wcvt_t_k(
    const float* __restrict__ W, bf16* __restrict__ WT, int K, int N)
{
    __shared__ float tile[32][33];
    W  += (size_t)blockIdx.z * K * N;
    WT += (size_t)blockIdx.z * K * N;
    const int tx = threadIdx.x & 31;
    const int ty4 = (threadIdx.x >> 5) * 4;
    const int n0 = blockIdx.x * 32, k0 = blockIdx.y * 32;
    #pragma unroll
    for (int r = 0; r < 4; ++r)
        tile[ty4 + r][tx] = (n0 + tx < N)
            ? W[(size_t)(k0 + ty4 + r) * N + n0 + tx] : 0.f;
    __syncthreads();
    #pragma unroll
    for (int r = 0; r < 4; ++r)
        if (n0 + ty4 + r < N)
            WT[(size_t)(n0 + ty4 + r) * K + k0 + tx] =
                __float2bfloat16(tile[tx][ty4 + r]);
}

// ---------------------------------------------------------------------------
// Flat fp32 -> bf16 convert
// ---------------------------------------------------------------------------
__global__ __launch_bounds__(256) void cvt_bf16_k(
    const float* __restrict__ in, bf16* __restrict__ out, int n)
{
    int i = blockIdx.x * 256 + threadIdx.x;
    if (i < n) out[i] = __float2bfloat16(in[i]);
}

// ---------------------------------------------------------------------------
// dt_w (all layers) [12][48][1536] -> dt_wT [12][1536][64], zero-pad k 48..63
// ---------------------------------------------------------------------------
__global__ __launch_bounds__(256) void dtw_cvt_k(
    const float* __restrict__ dt_w, bf16* __restrict__ dtwT)
{
    int idx = blockIdx.x * 256 + threadIdx.x;   // over 12*1536*64
    int k = idx & 63;
    int n = (idx >> 6) % D_INNER;
    int l = idx / (64 * D_INNER);
    dtwT[idx] = (k < DT_RANK)
        ? __float2bfloat16(dt_w[((size_t)l * DT_RANK + k) * D_INNER + n])
        : bf16(0.f);
}

// ---------------------------------------------------------------------------
// A2 (all layers): A2[l][d][n] = -exp(A_log[l][d][n]) * log2(e)
// ---------------------------------------------------------------------------
__global__ __launch_bounds__(256) void a2_k(
    const float* __restrict__ A_log, float* __restrict__ A2)
{
    int idx = blockIdx.x * 256 + threadIdx.x;   // < 12*1536*16
    A2[idx] = -expf(A_log[idx]) * LOG2E;
}

// ---------------------------------------------------------------------------
// bf16 MFMA GEMM, 64x64 tile (4 waves 2x2) — proven R10 body.
// EPI: 0 = store, 1 = bias+relu, 2 = bias+softplus, 3 = accumulate
// ---------------------------------------------------------------------------
template <int EPI, typename OT>
__global__ __launch_bounds__(256) void gemm_bf16(
    const bf16* __restrict__ A,
    const bf16* __restrict__ BT,
    OT* __restrict__ C, int ldc, int K,
    const float* __restrict__ bias)
{
    __shared__ __align__(16) char lds[2][16384];   // [buf][A 8K | B 8K]
    const int tid = threadIdx.x;
    const int lane = tid & 63;
    const int wid = tid >> 6;
    const int wr = wid >> 1, wc = wid & 1;
    const size_t rowBase = blockIdx.x * 64;
    const size_t colBase = blockIdx.y * 64;

    const int r0 = tid >> 3;
    const int cb0 = (tid & 7) * 16;
    const int slot = tid * 16;
    const size_t gOffSw = (size_t)r0 * K * 2 + (cb0 ^ ((r0 & 7) << 4));
    const size_t aStep = (size_t)32 * K * 2;   // +32 rows
    const char* gA = (const char*)(A + rowBase * K);
    const char* gB = (const char*)(BT + colBase * K);

    const int lrow = lane & 15;
    const int kg = (lane >> 4) * 16;
    const int swz = (lane & 7) << 4;

    f32x4 acc[2][2] = {};
    const int nt = K >> 6;

    {
        char* L = &lds[0][0];
        gl_lds16(gA + gOffSw,          L + slot);
        gl_lds16(gA + gOffSw + aStep,  L + 4096 + slot);
        gl_lds16(gB + gOffSw,          L + 8192 + slot);
        gl_lds16(gB + gOffSw + aStep,  L + 12288 + slot);
    }
    __syncthreads();

    for (int t = 0; t < nt; ++t) {
        const int cur = t & 1;
        if (t + 1 < nt) {
            char* L = &lds[cur ^ 1][0];
            size_t go = gOffSw + (size_t)(t + 1) * 128;
            gl_lds16(gA + go,          L + slot);
            gl_lds16(gA + go + aStep,  L + 4096 + slot);
            gl_lds16(gB + go,          L + 8192 + slot);
            gl_lds16(gB + go + aStep,  L + 12288 + slot);
        }
        #pragma unroll
        for (int kk = 0; kk < 2; ++kk) {
            const int col = (kk * 64 + kg) ^ swz;
            bf16x8 a0 = *(const bf16x8*)(&lds[cur][(wr * 32 +      lrow) * 128 + col]);
            bf16x8 a1 = *(const bf16x8*)(&lds[cur][(wr * 32 + 16 + lrow) * 128 + col]);
            bf16x8 b0 = *(const bf16x8*)(&lds[cur][8192 + (wc * 32 +      lrow) * 128 + col]);
            bf16x8 b1 = *(const bf16x8*)(&lds[cur][8192 + (wc * 32 + 16 + lrow) * 128 + col]);
            acc[0][0] = __builtin_amdgcn_mfma_f32_16x16x32_bf16(a0, b0, acc[0][0], 0, 0, 0);
            acc[0][1] = __builtin_amdgcn_mfma_f32_16x16x32_bf16(a0, b1, acc[0][1], 0, 0, 0);
            acc[1][0] = __builtin_amdgcn_mfma_f32_16x16x32_bf16(a1, b0, acc[1][0], 0, 0, 0);
            acc[1][1] = __builtin_amdgcn_mfma_f32_16x16x32_bf16(a1, b1, acc[1][1], 0, 0, 0);
        }
        __syncthreads();
    }

    const int mBase = (int)rowBase + wr * 32 + (lane >> 4) * 4;
    const int nBase = (int)colBase + wc * 32 + (lane & 15);
    #pragma unroll
    for (int i = 0; i < 2; ++i)
        #pragma unroll
        for (int j = 0; j < 2; ++j)
            #pragma unroll
            for (int rg = 0; rg < 4; ++rg) {
                int cc = nBase + j * 16;
                size_t idx = (size_t)(mBase + i * 16 + rg) * ldc + cc;
                float v = acc[i][j][rg];
                if (EPI == 0) {
                    C[idx] = (OT)v;
                } else if (EPI == 1) {
                    v += bias[cc];
                    C[idx] = (OT)(v > 0.f ? v : 0.f);
                } else if (EPI == 2) {
                    v += bias[cc];
                    C[idx] = (OT)softplus_f(v);
                } else {
                    C[idx] += v;
                }
            }
}

// ---------------------------------------------------------------------------
// Skinny split-K MFMA GEMM for xproj (no LDS); KSPLIT=16 -> 256 blocks
// ---------------------------------------------------------------------------
__global__ __launch_bounds__(256) void xproj_gemm_k(
    const bf16* __restrict__ xc_bf,
    const bf16* __restrict__ xprojT,
    float* __restrict__ part)
{
    const int lane = threadIdx.x & 63;
    const int w = threadIdx.x >> 6;
    const int m0 = blockIdx.x * 64 + w * 16;
    const int ks = blockIdx.y;
    const int KS = D_INNER / KSPLIT;          // 96
    const int k0 = ks * KS;

    const int arow = m0 + (lane & 15);
    const int kgrp = (lane >> 4) * 8;

    f32x4 acc[5] = {};
    const bf16* ap = xc_bf + (size_t)arow * D_INNER + kgrp;
    const bf16* bp = xprojT + (size_t)(lane & 15) * D_INNER + kgrp;

    for (int k = k0; k < k0 + KS; k += 32) {
        bf16x8 a = *(const bf16x8*)(ap + k);
        #pragma unroll
        for (int f = 0; f < 5; ++f) {
            bf16x8 b = *(const bf16x8*)(bp + (size_t)f * 16 * D_INNER + k);
            acc[f] = __builtin_amdgcn_mfma_f32_16x16x32_bf16(a, b, acc[f], 0, 0, 0);
        }
    }

    float* out = part + (size_t)ks * M_TOK * XPROJ_N;
    const int rowb = blockIdx.x * 64 + w * 16 + (lane >> 4) * 4;
    #pragma unroll
    for (int f = 0; f < 5; ++f)
        #pragma unroll
        for (int rg = 0; rg < 4; ++rg)
            out[(size_t)(rowb + rg) * XPROJ_N + f * 16 + (lane & 15)] = acc[f][rg];
}

// ---------------------------------------------------------------------------
// Reduce split-K partials -> xdbl fp32 [1024][80]; cols<48 also -> dtin bf16.
// Threads with col in [64,80) additionally zero dtin pad cols 48..63.
// ---------------------------------------------------------------------------
__global__ __launch_bounds__(256) void xproj_reduce_k(
    const float* __restrict__ part, float* __restrict__ xdbl,
    bf16* __restrict__ dtin)
{
    int idx = blockIdx.x * 256 + threadIdx.x;   // < 1024*80
    float s = 0.f;
    #pragma unroll
    for (int p = 0; p < KSPLIT; ++p)
        s += part[(size_t)p * M_TOK * XPROJ_N + idx];
    xdbl[idx] = s;
    int col = idx % XPROJ_N;
    int row = idx / XPROJ_N;
    if (col < DT_RANK)
        dtin[(size_t)row * 64 + col] = __float2bfloat16(s);
    else if (col >= 64)
        dtin[(size_t)row * 64 + col - 16] = bf16(0.f);
}

// ---------------------------------------------------------------------------
// RMSNorm: one block per token row; templated output type
// ---------------------------------------------------------------------------
template <typename OT>
__global__ __launch_bounds__(256) void rmsnorm_k(
    const float* __restrict__ x, const float* __restrict__ w,
    OT* __restrict__ o)
{
    const int row = blockIdx.x;
    const float* xr = x + (size_t)row * D_MODEL;
    float v[3];
    float s = 0.f;
    #pragma unroll
    for (int i = 0; i < 3; ++i) {
        v[i] = xr[threadIdx.x + i * 256];
        s = fmaf(v[i], v[i], s);
    }
    #pragma unroll
    for (int off = 32; off > 0; off >>= 1) s += __shfl_down(s, off);
    __shared__ float red[4];
    if ((threadIdx.x & 63) == 0) red[threadIdx.x >> 6] = s;
    __syncthreads();
    float tot = red[0] + red[1] + red[2] + red[3];
    float r = rsqrtf(tot * (1.f / D_MODEL) + 1e-5f);
    OT* orow = o + (size_t)row * D_MODEL;
    #pragma unroll
    for (int i = 0; i < 3; ++i) {
        int c = threadIdx.x + i * 256;
        orow[c] = (OT)(v[i] * r * w[c]);
    }
}

// ---------------------------------------------------------------------------
// Causal depthwise conv (width 4) + bias + silu; vectorized 8 d / thread
// ---------------------------------------------------------------------------
__global__ __launch_bounds__(256) void conv_silu_k(
    const bf16* __restrict__ xz, const float* __restrict__ cw,
    const float* __restrict__ cb, bf16* __restrict__ xc_bf)
{
    int v = blockIdx.x * 256 + threadIdx.x;   // over M_TOK*D_INNER/8
    int d8 = (v * 8) % D_INNER;
    int bt = (v * 8) / D_INNER;
    int t = bt & (SEQ - 1);
    int b = bt >> 8;

    float acc[8];
    {
        const float4* cbp = (const float4*)(cb + d8);
        float4 c0 = cbp[0], c1 = cbp[1];
        acc[0] = c0.x; acc[1] = c0.y; acc[2] = c0.z; acc[3] = c0.w;
        acc[4] = c1.x; acc[5] = c1.y; acc[6] = c1.z; acc[7] = c1.w;
    }
    float4 wv[8];
    #pragma unroll
    for (int j = 0; j < 8; ++j)
        wv[j] = *(const float4*)(cw + (size_t)(d8 + j) * 4);

    #pragma unroll
    for (int k = 0; k < 4; ++k) {
        int tt = t - 3 + k;
        if (tt >= 0) {
            u16x8 xv = *(const u16x8*)(xz + (size_t)(b * SEQ + tt) * (2 * D_INNER) + d8);
            #pragma unroll
            for (int j = 0; j < 8; ++j) {
                float wk = (k == 0) ? wv[j].x : (k == 1) ? wv[j].y
                         : (k == 2) ? wv[j].z : wv[j].w;
                acc[j] = fmaf(us2f(xv[j]), wk, acc[j]);
            }
        }
    }

    __align__(16) bf16 ob[8];
    #pragma unroll
    for (int j = 0; j < 8; ++j) {
        float a = acc[j];
        float s = a / (1.f + expf(-a));
        ob[j] = __float2bfloat16(s);
    }
    *(uint4*)(xc_bf + (size_t)v * 8) = *(const uint4*)ob;
}

// ---------------------------------------------------------------------------
// Chunked scan phase 1 (h-only): per (b, chunk, d) evolve state from h=0.
// Writes chunk-final h (hpart) and chunk dv-sum (dvsum). No y work.
// ---------------------------------------------------------------------------
__global__ __launch_bounds__(256) void scan_part_k(
    const bf16* __restrict__ delta,
    const bf16* __restrict__ xc,
    const float* __restrict__ xdbl,
    const float* __restrict__ A2,
    float* __restrict__ dvsum,
    float* __restrict__ hpart)
{
    __shared__ float sB[CLEN][16];
    const int tid = threadIdx.x;
    const int dgrp  = blockIdx.x % 6;
    const int chunk = (blockIdx.x / 6) & (NCHUNK - 1);
    const int b     = blockIdx.x / (6 * NCHUNK);
    const int d  = dgrp * 256 + tid;
    const int t0 = chunk * CLEN;

    if (tid < CLEN * 16) {
        int r = tid >> 4, c = tid & 15;
        sB[r][c] = xdbl[(size_t)(b * SEQ + t0 + r) * XPROJ_N + DT_RANK + c];
    }

    float a2[16];
    {
        const float4* ap = (const float4*)(A2 + (size_t)d * 16);
        #pragma unroll
        for (int q = 0; q < 4; ++q) {
            float4 vv = ap[q];
            a2[q * 4 + 0] = vv.x; a2[q * 4 + 1] = vv.y;
            a2[q * 4 + 2] = vv.z; a2[q * 4 + 3] = vv.w;
        }
    }

    const size_t base = (size_t)(b * SEQ + t0) * D_INNER + d;
    const bf16* dp = delta + base;
    const bf16* up = xc + base;

    float dvv[CLEN], uvv[CLEN];
    #pragma unroll
    for (int s = 0; s < CLEN; ++s) {
        dvv[s] = b2f(dp[(size_t)s * D_INNER]);
        uvv[s] = b2f(up[(size_t)s * D_INNER]);
    }
    __syncthreads();

    float h[16];
    #pragma unroll
    for (int n = 0; n < 16; ++n) h[n] = 0.f;
    float cum = 0.f;

    #pragma unroll
    for (int s = 0; s < CLEN; ++s) {
        float dv = dvv[s];
        cum += dv;
        float du = dv * uvv[s];
        #pragma unroll
        for (int n = 0; n < 16; ++n) {
            float dA = exp2f(dv * a2[n]);
            h[n] = fmaf(dA, h[n], du * sB[s][n]);
        }
    }

    dvsum[((size_t)b * NCHUNK + chunk) * D_INNER + d] = cum;
    float4* hp = (float4*)(hpart + (((size_t)b * NCHUNK + chunk) * D_INNER + d) * 16);
    #pragma unroll
    for (int q = 0; q < 4; ++q) {
        float4 vv;
        vv.x = h[q * 4 + 0]; vv.y = h[q * 4 + 1];
        vv.z = h[q * 4 + 2]; vv.w = h[q * 4 + 3];
        hp[q] = vv;
    }
}

// ---------------------------------------------------------------------------
// Phase 2: serial prefix over chunks. Thread = (b,d,n).
// ---------------------------------------------------------------------------
__global__ __launch_bounds__(256) void scan_pref_k(
    const float* __restrict__ dvsum,
    const float* __restrict__ hpart,
    const float* __restrict__ A2,
    float* __restrict__ hinb)
{
    int idx = blockIdx.x * 256 + threadIdx.x;   // < 4*1536*16
    int n = idx & 15;
    int r = idx >> 4;
    int d = r % D_INNER;
    int b = r / D_INNER;
    float a2 = A2[(size_t)d * 16 + n];
    float hin = 0.f;
    #pragma unroll
    for (int c = 0; c < NCHUNK; ++c) {
        hinb[(((size_t)b * NCHUNK + c) * D_INNER + d) * 16 + n] = hin;
        float sdv = dvsum[((size_t)b * NCHUNK + c) * D_INNER + d];
        float hp  = hpart[(((size_t)b * NCHUNK + c) * D_INNER + d) * 16 + n];
        hin = fmaf(hin, exp2f(a2 * sdv), hp);
    }
}

// ---------------------------------------------------------------------------
// Phase 3 (final): redo the within-chunk scan starting from hinb and emit
// y = (C·h + u*D) * silu(res) directly. Same body/register pattern as phase1.
// ---------------------------------------------------------------------------
__global__ __launch_bounds__(256) void scan_fin_k(
    const bf16* __restrict__ delta,
    const bf16* __restrict__ xc,
    const float* __restrict__ xdbl,
    const bf16* __restrict__ xz,
    const float* __restrict__ A2,
    const float* __restrict__ D_param,
    const float* __restrict__ hinb,
    bf16* __restrict__ y)
{
    __shared__ float sBC[CLEN][32];   // [step][B 0..15 | C 16..31]
    const int tid = threadIdx.x;
    const int dgrp  = blockIdx.x % 6;
    const int chunk = (blockIdx.x / 6) & (NCHUNK - 1);
    const int b     = blockIdx.x / (6 * NCHUNK);
    const int d  = dgrp * 256 + tid;
    const int t0 = chunk * CLEN;

    {
        int r = tid >> 5, c = tid & 31;
        sBC[r][c]     = xdbl[(size_t)(b * SEQ + t0 + r) * XPROJ_N + DT_RANK + c];
        sBC[r + 8][c] = xdbl[(size_t)(b * SEQ + t0 + r + 8) * XPROJ_N + DT_RANK + c];
    }

    float a2[16];
    {
        const float4* ap = (const float4*)(A2 + (size_t)d * 16);
        #pragma unroll
        for (int q = 0; q < 4; ++q) {
            float4 vv = ap[q];
            a2[q * 4 + 0] = vv.x; a2[q * 4 + 1] = vv.y;
            a2[q * 4 + 2] = vv.z; a2[q * 4 + 3] = vv.w;
        }
    }
    const float Dp = D_param[d];

    const size_t base = (size_t)(b * SEQ + t0) * D_INNER + d;
    const bf16* dp = delta + base;
    const bf16* up = xc + base;
    const bf16* rp = xz + (size_t)(b * SEQ + t0) * 2 * D_INNER + D_INNER + d;
    bf16* yp = y + base;

    float dvv[CLEN], uvv[CLEN];
    #pragma unroll
    for (int s = 0; s < CLEN; ++s) {
        dvv[s] = b2f(dp[(size_t)s * D_INNER]);
        uvv[s] = b2f(up[(size_t)s * D_INNER]);
    }

    float h[16];
    {
        const float4* hp = (const float4*)(hinb + (((size_t)b * NCHUNK + chunk) * D_INNER + d) * 16);
        #pragma unroll
        for (int q = 0; q < 4; ++q) {
            float4 vv = hp[q];
            h[q * 4 + 0] = vv.x; h[q * 4 + 1] = vv.y;
            h[q * 4 + 2] = vv.z; h[q * 4 + 3] = vv.w;
        }
    }
    __syncthreads();

    #pragma unroll
    for (int s = 0; s < CLEN; ++s) {
        float dv = dvv[s], u = uvv[s];
        float du = dv * u;
        float yv = 0.f;
        #pragma unroll
        for (int n = 0; n < 16; ++n) {
            float dA = exp2f(dv * a2[n]);
            h[n] = fmaf(dA, h[n], du * sBC[s][n]);
            yv = fmaf(h[n], sBC[s][16 + n], yv);
        }
        float res = b2f(rp[(size_t)s * 2 * D_INNER]);
        float sr = res / (1.f + expf(-res));
        yp[(size_t)s * D_INNER] =
            __float2bfloat16(fmaf(u, Dp, yv) * sr);
    }
}

// ---------------------------------------------------------------------------
// Launch
// ---------------------------------------------------------------------------
extern "C" void kernel_launch(void* const* d_in, const int* in_sizes, int n_in,
                              void* d_out, int out_size, void* d_ws, size_t ws_size,
                              hipStream_t stream)
{
    const float* frames  = (const float*)d_in[0];
    const float* fproj_w = (const float*)d_in[1];
    const float* fproj_b = (const float*)d_in[2];
    const float* norm_w  = (const float*)d_in[3];
    const float* in_w    = (const float*)d_in[4];
    const float* conv_w  = (const float*)d_in[5];
    const float* conv_b  = (const float*)d_in[6];
    const float* xproj_w = (const float*)d_in[7];
    const float* dt_w    = (const float*)d_in[8];
    const float* dt_b    = (const float*)d_in[9];
    const float* A_log   = (const float*)d_in[10];
    const float* D_param = (const float*)d_in[11];
    const float* out_w   = (const float*)d_in[12];
    const float* normf_w = (const float*)d_in[13];

    // workspace layout
    char* ws = (char*)d_ws;
    float* h      = (float*)ws;        ws += (size_t)M_TOK * D_MODEL * 4;
    float* xdbl   = (float*)ws;        ws += (size_t)M_TOK * XPROJ_N * 4;
    float* part   = (float*)ws;        ws += (size_t)KSPLIT * M_TOK * XPROJ_N * 4;
    float* dvsum  = (float*)ws;        ws += (size_t)BATCH * NCHUNK * D_INNER * 4;
    float* hpartb = (float*)ws;        ws += (size_t)BATCH * NCHUNK * D_INNER * 16 * 4;
    float* hinb   = (float*)ws;        ws += (size_t)BATCH * NCHUNK * D_INNER * 16 * 4;
    float* A2all  = (float*)ws;        ws += (size_t)N_LAYER * D_INNER * 16 * 4;
    bf16* xz_bf   = (bf16*)ws;         ws += (size_t)M_TOK * 2 * D_INNER * 2;
    bf16* xc_bf   = (bf16*)ws;         ws += (size_t)M_TOK * D_INNER * 2;
    bf16* delta_bf= (bf16*)ws;         ws += (size_t)M_TOK * D_INNER * 2;
    bf16* x_bf    = (bf16*)ws;         ws += (size_t)M_TOK * D_MODEL * 2;
    bf16* y_bf    = (bf16*)ws;         ws += (size_t)M_TOK * D_INNER * 2;
    bf16* dtin    = (bf16*)ws;         ws += (size_t)M_TOK * 64 * 2;
    bf16* fr_bf   = (bf16*)ws;         ws += (size_t)M_TOK * IMG_DIM * 2;
    bf16* fp_wT   = (bf16*)ws;         ws += (size_t)D_MODEL * IMG_DIM * 2;
    bf16* in_wT   = (bf16*)ws;         ws += (size_t)N_LAYER * 2 * D_INNER * D_MODEL * 2;
    bf16* out_wT  = (bf16*)ws;         ws += (size_t)N_LAYER * D_MODEL * D_INNER * 2;
    bf16* xprojT  = (bf16*)ws;         ws += (size_t)N_LAYER * XPROJ_N * D_INNER * 2;
    bf16* dt_wT   = (bf16*)ws;         ws += (size_t)N_LAYER * D_INNER * 64 * 2;

    dim3 blk(256);

    // --- once-per-call preprocessing (batched over all layers) ---
    cvt_bf16_k<<<(M_TOK * IMG_DIM) / 256, blk, 0, stream>>>(
        frames, fr_bf, M_TOK * IMG_DIM);
    wcvt_t_k<<<dim3(D_MODEL / 32, IMG_DIM / 32, 1), blk, 0, stream>>>(
        fproj_w, fp_wT, IMG_DIM, D_MODEL);
    wcvt_t_k<<<dim3(2 * D_INNER / 32, D_MODEL / 32, N_LAYER), blk, 0, stream>>>(
        in_w, in_wT, D_MODEL, 2 * D_INNER);
    wcvt_t_k<<<dim3(D_MODEL / 32, D_INNER / 32, N_LAYER), blk, 0, stream>>>(
        out_w, out_wT, D_INNER, D_MODEL);
    wcvt_t_k<<<dim3((XPROJ_N + 31) / 32, D_INNER / 32, N_LAYER), blk, 0, stream>>>(
        xproj_w, xprojT, D_INNER, XPROJ_N);
    dtw_cvt_k<<<(N_LAYER * D_INNER * 64) / 256, blk, 0, stream>>>(dt_w, dt_wT);
    a2_k<<<(N_LAYER * D_INNER * 16) / 256, blk, 0, stream>>>(A_log, A2all);

    // h = relu(frames @ fproj_w + fproj_b)
    gemm_bf16<1, float><<<dim3(M_TOK / 64, D_MODEL / 64), blk, 0, stream>>>(
        fr_bf, fp_wT, h, D_MODEL, IMG_DIM, fproj_b);

    for (int i = 0; i < N_LAYER; ++i) {
        const bf16* in_wTi   = in_wT  + (size_t)i * 2 * D_INNER * D_MODEL;
        const bf16* out_wTi  = out_wT + (size_t)i * D_MODEL * D_INNER;
        const bf16* xprojTi  = xprojT + (size_t)i * XPROJ_N * D_INNER;
        const bf16* dt_wTi   = dt_wT  + (size_t)i * D_INNER * 64;
        const float* A2i     = A2all  + (size_t)i * D_INNER * 16;
        const float* conv_wi = conv_w + (size_t)i * D_INNER * D_CONV;
        const float* conv_bi = conv_b + (size_t)i * D_INNER;
        const float* dt_bi   = dt_b   + (size_t)i * D_INNER;
        const float* D_parami= D_param+ (size_t)i * D_INNER;
        const float* norm_wi = norm_w + (size_t)i * D_MODEL;

        rmsnorm_k<bf16><<<M_TOK, blk, 0, stream>>>(h, norm_wi, x_bf);
        gemm_bf16<0, bf16><<<dim3(M_TOK / 64, (2 * D_INNER) / 64), blk, 0, stream>>>(
            x_bf, in_wTi, xz_bf, 2 * D_INNER, D_MODEL, nullptr);
        conv_silu_k<<<(M_TOK * D_INNER / 8) / 256, blk, 0, stream>>>(
            xz_bf, conv_wi, conv_bi, xc_bf);
        xproj_gemm_k<<<dim3(M_TOK / 64, KSPLIT), blk, 0, stream>>>(
            xc_bf, xprojTi, part);
        xproj_reduce_k<<<(M_TOK * XPROJ_N) / 256, blk, 0, stream>>>(
            part, xdbl, dtin);
        gemm_bf16<2, bf16><<<dim3(M_TOK / 64, D_INNER / 64), blk, 0, stream>>>(
            dtin, dt_wTi, delta_bf, D_INNER, 64, dt_bi);
        scan_part_k<<<BATCH * NCHUNK * (D_INNER / 256), blk, 0, stream>>>(
            delta_bf, xc_bf, xdbl, A2i, dvsum, hpartb);
        scan_pref_k<<<(BATCH * D_INNER * 16) / 256, blk, 0, stream>>>(
            dvsum, hpartb, A2i, hinb);
        scan_fin_k<<<BATCH * NCHUNK * (D_INNER / 256), blk, 0, stream>>>(
            delta_bf, xc_bf, xdbl, xz_bf, A2i, D_parami, hinb, y_bf);
        gemm_bf16<3, float><<<dim3(M_TOK / 64, D_MODEL / 64), blk, 0, stream>>>(
            y_bf, out_wTi, h, D_MODEL, D_INNER, nullptr);
    }

    // out = rmsnorm(h, normf_w)  (fp32)
    rmsnorm_k<float><<<M_TOK, blk, 0, stream>>>(h, normf_w, (float*)d_out);
}